// Round 2
// baseline (801.004 us; speedup 1.0000x reference)
//
#include <hip/hip_runtime.h>
#include <string.h>

#define B_SZ 16
#define L_SZ 1024
#define D_SZ 256
#define KW   16
#define LP   (L_SZ + KW - 1)   /* 1039 padded rows per batch */
#define G3   (3 * D_SZ)        /* 768 */

typedef float f32x4 __attribute__((ext_vector_type(4)));
typedef short bf16x8 __attribute__((ext_vector_type(8)));
typedef unsigned int u32x4 __attribute__((ext_vector_type(4)));

__device__ __forceinline__ float bf2f(unsigned short u) {
    union { unsigned int i; float f; } v; v.i = ((unsigned int)u) << 16; return v.f;
}
__device__ __forceinline__ unsigned short f2bf(float f) {
    union { float f; unsigned int i; } v; v.f = f;
    unsigned int r = v.i + 0x7fffu + ((v.i >> 16) & 1u);
    return (unsigned short)(r >> 16);
}
__device__ __forceinline__ float fast_sigmoid(float x) {
    float e = __builtin_amdgcn_exp2f(-1.44269504f * x);
    return __builtin_amdgcn_rcpf(1.0f + e);
}
__device__ __forceinline__ float fast_tanh(float x) {
    float e = __builtin_amdgcn_exp2f(-2.88539008f * x);
    return (1.0f - e) * __builtin_amdgcn_rcpf(1.0f + e);
}
__device__ __forceinline__ f32x4 zero4() { f32x4 v; v[0]=0.f; v[1]=0.f; v[2]=0.f; v[3]=0.f; return v; }

// ---------------------------------------------------------------------------
// prep: fp32 -> bf16 conversions + fill gi pad rows (t<15) with b_ih (fp32)
// ---------------------------------------------------------------------------
__global__ void prep_kernel(const float* __restrict__ x,
                            const float* __restrict__ wih,
                            const float* __restrict__ whh,
                            const float* __restrict__ bih,
                            unsigned short* __restrict__ xbf,
                            unsigned short* __restrict__ wihbf,
                            unsigned short* __restrict__ whhbf,
                            float* __restrict__ gi) {
    const int NX = B_SZ * L_SZ * D_SZ;      // 4194304
    const int NW = G3 * D_SZ;               // 196608
    const int NP = B_SZ * (KW - 1) * G3;    // 184320
    const int total = NX + 2 * NW + NP;
    for (int i = blockIdx.x * blockDim.x + threadIdx.x; i < total;
         i += gridDim.x * blockDim.x) {
        if (i < NX) {
            xbf[i] = f2bf(x[i]);
        } else if (i < NX + NW) {
            wihbf[i - NX] = f2bf(wih[i - NX]);
        } else if (i < NX + 2 * NW) {
            whhbf[i - NX - NW] = f2bf(whh[i - NX - NW]);
        } else {
            int p = i - NX - 2 * NW;        // [B][15][768]
            int n = p % G3;
            int bt = p / G3;
            int b = bt / (KW - 1);
            int t = bt % (KW - 1);
            gi[((size_t)b * LP + t) * G3 + n] = bih[n];
        }
    }
}

// ---------------------------------------------------------------------------
// gi GEMM: gi[b][15+l][n] = sum_d x[b][l][d]*W_ih[n][d] + b_ih[n]  (fp32 out)
// 256 blocks (one 64-row tile each), 8 waves, wave owns 32 dims x 3 gates
// ---------------------------------------------------------------------------
__global__ __launch_bounds__(512, 2) void gi_gemm_kernel(
    const unsigned short* __restrict__ xbf,    // [B*L][256]
    const unsigned short* __restrict__ wihbf,  // [768][256]
    const float* __restrict__ bih,             // [768]
    float* __restrict__ gi) {                  // [B][LP][768]
    __shared__ unsigned short xt[64 * 256];
    const int tid = threadIdx.x;
    const int wid = tid >> 6, lane = tid & 63;
    const int b = blockIdx.x >> 4;
    const int l0 = (blockIdx.x & 15) << 6;
    const int grow0 = b * L_SZ + l0;

    // stage x tile into LDS, XOR-swizzled (byte ^= (row&7)<<4)
    for (int c = tid; c < 2048; c += 512) {
        int byte = c * 16;
        int row = byte >> 9;
        int colb = byte & 511;
        u32x4 v = *(const u32x4*)(xbf + (size_t)(grow0 + row) * 256 + (colb >> 1));
        *(u32x4*)((char*)xt + (row * 512 + (colb ^ ((row & 7) << 4)))) = v;
    }
    __syncthreads();

    const int d0 = wid << 5;
    const int colg = lane & 15;
    const int kg = lane >> 4;

    f32x4 acc[3][2][4];
#pragma unroll
    for (int g = 0; g < 3; g++)
#pragma unroll
        for (int dn = 0; dn < 2; dn++)
#pragma unroll
            for (int mt = 0; mt < 4; mt++) acc[g][dn][mt] = zero4();

#pragma unroll
    for (int ks = 0; ks < 8; ks++) {
        bf16x8 a[4];
#pragma unroll
        for (int mt = 0; mt < 4; mt++) {
            int row = mt * 16 + colg;
            int off = row * 512 + ((ks * 64 + kg * 16) ^ ((row & 7) << 4));
            a[mt] = *(const bf16x8*)((const char*)xt + off);
        }
#pragma unroll
        for (int g = 0; g < 3; g++) {
#pragma unroll
            for (int dn = 0; dn < 2; dn++) {
                int n = g * 256 + d0 + dn * 16 + colg;
                bf16x8 bw = *(const bf16x8*)(wihbf + (size_t)n * 256 + ks * 32 + kg * 8);
#pragma unroll
                for (int mt = 0; mt < 4; mt++)
                    acc[g][dn][mt] = __builtin_amdgcn_mfma_f32_16x16x32_bf16(
                        a[mt], bw, acc[g][dn][mt], 0, 0, 0);
            }
        }
    }

#pragma unroll
    for (int g = 0; g < 3; g++) {
#pragma unroll
        for (int dn = 0; dn < 2; dn++) {
            int n = g * 256 + d0 + dn * 16 + colg;
            float bias = bih[n];
#pragma unroll
            for (int mt = 0; mt < 4; mt++) {
#pragma unroll
                for (int rr = 0; rr < 4; rr++) {
                    int row = mt * 16 + kg * 4 + rr;
                    gi[((size_t)b * LP + (KW - 1) + l0 + row) * G3 + n] =
                        acc[g][dn][mt][rr] + bias;
                }
            }
        }
    }
}

// ---------------------------------------------------------------------------
// recurrence: 256 blocks x 64 sequences, 16 GRU steps.
// h state fp32 in registers (wave owns its 32 dims); bf16 copy of h in LDS
// (double-buffered, swizzled) is the MFMA A-operand for all waves.
// ---------------------------------------------------------------------------
__global__ __launch_bounds__(512, 2) void rnn_kernel(
    const float* __restrict__ gi,              // [B][LP][768] fp32
    const unsigned short* __restrict__ whhbf,  // [768][256]   bf16
    const float* __restrict__ bhh,             // [768]
    float* __restrict__ out) {                 // [B*L][256] fp32
    __shared__ unsigned short hb[2][64 * 256];
    const int tid = threadIdx.x;
    const int wid = tid >> 6, lane = tid & 63;
    const int b = blockIdx.x >> 4;
    const int l0 = (blockIdx.x & 15) << 6;
    const int d0 = wid << 5;
    const int colg = lane & 15;
    const int kg = lane >> 4;

    // zero h buffer 0
    {
        u32x4 z; z[0] = 0u; z[1] = 0u; z[2] = 0u; z[3] = 0u;
        for (int c = tid; c < 2048; c += 512)
            *(u32x4*)((char*)hb[0] + c * 16) = z;
    }

    f32x4 hst[2][4];
#pragma unroll
    for (int dn = 0; dn < 2; dn++)
#pragma unroll
        for (int mt = 0; mt < 4; mt++) hst[dn][mt] = zero4();

    float bh[3][2];
#pragma unroll
    for (int g = 0; g < 3; g++)
#pragma unroll
        for (int dn = 0; dn < 2; dn++)
            bh[g][dn] = bhh[g * 256 + d0 + dn * 16 + colg];

    __syncthreads();

#pragma unroll 1
    for (int k = 0; k < KW; k++) {
        const unsigned short* hcur = hb[k & 1];
        unsigned short* hnxt = hb[(k & 1) ^ 1];

        f32x4 acc[3][2][4];
#pragma unroll
        for (int g = 0; g < 3; g++)
#pragma unroll
            for (int dn = 0; dn < 2; dn++)
#pragma unroll
                for (int mt = 0; mt < 4; mt++) acc[g][dn][mt] = zero4();

        if (k > 0) {  // k==0: h==0 -> gh==0, skip GEMM
#pragma unroll
            for (int ks = 0; ks < 8; ks++) {
                bf16x8 a[4];
#pragma unroll
                for (int mt = 0; mt < 4; mt++) {
                    int row = mt * 16 + colg;
                    int off = row * 512 + ((ks * 64 + kg * 16) ^ ((row & 7) << 4));
                    a[mt] = *(const bf16x8*)((const char*)hcur + off);
                }
#pragma unroll
                for (int g = 0; g < 3; g++) {
#pragma unroll
                    for (int dn = 0; dn < 2; dn++) {
                        int n = g * 256 + d0 + dn * 16 + colg;
                        bf16x8 bw = *(const bf16x8*)(whhbf + (size_t)n * 256 + ks * 32 + kg * 8);
#pragma unroll
                        for (int mt = 0; mt < 4; mt++)
                            acc[g][dn][mt] = __builtin_amdgcn_mfma_f32_16x16x32_bf16(
                                a[mt], bw, acc[g][dn][mt], 0, 0, 0);
                    }
                }
            }
        }

        // gate math (wave-local dims), update fp32 h state, write bf16 h to LDS
        const float* gbase = gi + ((size_t)(b * LP) + l0 + k) * G3;
#pragma unroll
        for (int mt = 0; mt < 4; mt++) {
#pragma unroll
            for (int dn = 0; dn < 2; dn++) {
                const int dcol = d0 + dn * 16 + colg;
#pragma unroll
                for (int rr = 0; rr < 4; rr++) {
                    int row = mt * 16 + kg * 4 + rr;
                    size_t go = (size_t)row * G3 + dcol;
                    float ir = gbase[go];
                    float iz = gbase[go + 256];
                    float in_ = gbase[go + 512];
                    float hr = acc[0][dn][mt][rr] + bh[0][dn];
                    float hz = acc[1][dn][mt][rr] + bh[1][dn];
                    float hn = acc[2][dn][mt][rr] + bh[2][dn];
                    float r = fast_sigmoid(ir + hr);
                    float z = fast_sigmoid(iz + hz);
                    float n = fast_tanh(in_ + r * hn);
                    float h = hst[dn][mt][rr];
                    float hnew = n + z * (h - n);
                    hst[dn][mt][rr] = hnew;
                    int off = row * 512 + ((dcol * 2) ^ ((row & 7) << 4));
                    *(unsigned short*)((char*)hnxt + off) = f2bf(hnew);
                }
            }
        }
        __syncthreads();
    }

    // epilogue: final h (fp32 registers) -> out
#pragma unroll
    for (int dn = 0; dn < 2; dn++) {
        const int dcol = d0 + dn * 16 + colg;
#pragma unroll
        for (int mt = 0; mt < 4; mt++) {
#pragma unroll
            for (int rr = 0; rr < 4; rr++) {
                int row = mt * 16 + kg * 4 + rr;
                out[(size_t)(b * L_SZ + l0 + row) * D_SZ + dcol] = hst[dn][mt][rr];
            }
        }
    }
}

// ---------------------------------------------------------------------------
extern "C" void kernel_launch(void* const* d_in, const int* in_sizes, int n_in,
                              void* d_out, int out_size, void* d_ws, size_t ws_size,
                              hipStream_t stream) {
    const float* x   = (const float*)d_in[0];
    const float* wih = (const float*)d_in[1];
    const float* whh = (const float*)d_in[2];
    const float* bih = (const float*)d_in[3];
    const float* bhh = (const float*)d_in[4];
    float* out = (float*)d_out;

    char* ws = (char*)d_ws;
    unsigned short* xbf   = (unsigned short*)(ws);              // 8,388,608 B
    unsigned short* wihbf = (unsigned short*)(ws + 8388608);    //   393,216 B
    unsigned short* whhbf = (unsigned short*)(ws + 8781824);    //   393,216 B
    float*          gi    = (float*)(ws + 9175040);             // 51,068,928 B

    prep_kernel<<<2048, 256, 0, stream>>>(x, wih, whh, bih, xbf, wihbf, whhbf, gi);
    gi_gemm_kernel<<<256, 512, 0, stream>>>(xbf, wihbf, bih, gi);
    rnn_kernel<<<256, 512, 0, stream>>>(gi, whhbf, bhh, out);
}